// Round 12
// baseline (85.094 us; speedup 1.0000x reference)
//
#include <hip/hip_runtime.h>
#include <math.h>

// ---------------------------------------------------------------------------
// Z_exp = Tr(M rho^x4) = degree-4 poly in Bloch (x,y,z), 35 monomials.
// R10 best (23.7us): chain ~18us across 8 barrier-separated 4-wave phases.
// R12 probe: chain on ONE wave (wave 0), wave-synchronous — phases separated
// by s_waitcnt lgkmcnt(0)+sched_barrier only (no __syncthreads); each lane
// owns a 4-entry row-quad per 16x16 matrix -> wide batched ds_reads (unlike
// R6's serialized shuffles). Waves 1-7 do all eval prep concurrently; ONE
// barrier total, then eval finish. Tests "barrier-phase overhead" theory.
// ---------------------------------------------------------------------------

struct cpx { float re, im; };

__device__ __forceinline__ cpx cmul(cpx a, cpx b) {
    return { a.re * b.re - a.im * b.im, a.re * b.im + a.im * b.re };
}
__device__ __forceinline__ cpx cfma_(cpx acc, cpx a, cpx b) {
    acc.re += a.re * b.re - a.im * b.im;
    acc.im += a.re * b.im + a.im * b.re;
    return acc;
}

// ---- compile-time Pauli-string -> monomial grouping (data-independent) ----
struct MonoTab { unsigned char cnt[125]; unsigned char idx[125][24]; };

constexpr int mono_of(int p) {
    int a = 0, b = 0, c = 0;
    for (int k = 0; k < 4; ++k) {
        const int pk = (p >> (2 * k)) & 3;   // 0=I,1=X,2=Y,3=Z
        a += (pk == 1); b += (pk == 2); c += (pk == 3);
    }
    return (a * 5 + b) * 5 + c;
}
constexpr MonoTab build_tab() {
    MonoTab t{};
    for (int m = 0; m < 125; ++m) {
        t.cnt[m] = 0;
        for (int k = 0; k < 24; ++k) t.idx[m][k] = 0;
    }
    for (int p = 0; p < 256; ++p) {          // ascending p: fixed sum order
        const int m = mono_of(p);
        t.idx[m][t.cnt[m]++] = (unsigned char)p;
    }
    return t;
}
__constant__ const MonoTab TAB = build_tab();

// wave-synchronous phase separator (rule #18: sched_barrier after asm waitcnt)
#define WSYNC do { asm volatile("s_waitcnt lgkmcnt(0)" ::: "memory"); \
                   __builtin_amdgcn_sched_barrier(0); } while (0)

__global__ __launch_bounds__(512) void fused_kernel(
    const float4* __restrict__ in4, const float* __restrict__ w_U,
    const float* __restrict__ w_RXZX, const float* __restrict__ scale_p,
    const float* __restrict__ bias_p, float2* __restrict__ out2, int B2)
{
    __shared__ cpx   R[24][2][2];
    __shared__ float ISc[6], ISs[6];
    __shared__ cpx   Lm[6][16][16];
    __shared__ cpx   P1[3][16][16];
    __shared__ cpx   Dm[16][16];
    __shared__ cpx   Wf[16][16];
    __shared__ cpx   Mm[16][16];
    __shared__ float cp[256];
    __shared__ float cf[125];

    const int tid = threadIdx.x;

    // ================= EVAL PREP (waves 1-7), overlaps the chain ===========
    float xp[2][5], yp[2][5], zp[2][5];
    float scale = 0.f, bias = 0.f;
    int gidx = 0;
    if (tid >= 64) {
        gidx = blockIdx.x * 448 + (tid - 64);
        float4 f = make_float4(0.f, 0.f, 0.f, 0.f);
        if (gidx < B2) f = in4[gidx];
        scale = scale_p[0];
        bias  = bias_p[0];
        #pragma unroll
        for (int e = 0; e < 2; ++e) {
            const float f0 = e ? f.z : f.x;
            const float f1 = e ? f.w : f.y;
            float s0, c0, s1, c1;
            sincosf(f0, &s0, &c0);
            sincosf(f1, &s1, &c1);
            const float x = s1 * c0, y = s1 * s0, z = c1;
            xp[e][0] = yp[e][0] = zp[e][0] = 1.f;
            #pragma unroll
            for (int k = 1; k < 5; ++k) {
                xp[e][k] = xp[e][k - 1] * x;
                yp[e][k] = yp[e][k - 1] * y;
                zp[e][k] = zp[e][k - 1] * z;
            }
        }
    }

    // ================= CHAIN: wave 0, wave-synchronous =====================
    if (tid < 64) {
        // ---- Phase A: 2x2 RXZX gates + iSWAP params ----
        if (tid < 24) {
            const float ta = w_RXZX[tid * 3 + 0];
            const float tb = w_RXZX[tid * 3 + 1];
            const float tc = w_RXZX[tid * 3 + 2];
            float sa, ca, sb, cb, sc, c2;
            sincosf(0.5f * ta, &sa, &ca);
            sincosf(0.5f * tb, &sb, &cb);
            sincosf(0.5f * tc, &sc, &c2);
            // RX(t)=[[c,-is],[-is,c]], RZ(t)=diag(c-is,c+is); g=RX(a)RZ(b)RX(c)
            const cpx e0 = { cb, -sb };
            const cpx e1 = { cb,  sb };
            const cpx T00 = { e0.re * c2, e0.im * c2 };
            const cpx T01 = { -e0.im * (-sc), e0.re * (-sc) };
            const cpx T10 = { -e1.im * (-sc), e1.re * (-sc) };
            const cpx T11 = { e1.re * c2, e1.im * c2 };
            R[tid][0][0] = { ca * T00.re + sa * T10.im, ca * T00.im - sa * T10.re };
            R[tid][0][1] = { ca * T01.re + sa * T11.im, ca * T01.im - sa * T11.re };
            R[tid][1][0] = { sa * T00.im + ca * T10.re, -sa * T00.re + ca * T10.im };
            R[tid][1][1] = { sa * T01.im + ca * T11.re, -sa * T01.re + ca * T11.im };
        } else if (tid < 30) {
            const int l = tid - 24;
            float s, c;
            sincosf(w_U[l], &s, &c);
            ISc[l] = c;
            ISs[l] = s;
        }
        WSYNC;

        const int i = tid >> 2;            // row 0..15
        const int j0 = (tid & 3) << 2;     // col quad base

        // ---- Phase B: Lm[l] = (GA on iSWAP pair) (x) (GB on complement) ----
        // PAIR byte per layer l: qa|qb<<2|qr<<4|qs<<6;
        // PAIRS=[(1,2),(1,3),(1,2),(1,3),(0,3),(0,2)]
        for (int l = 0; l < 6; ++l) {
            const int code = (int)((0xD89C8DC98DC9ULL >> (8 * l)) & 0xFF);
            const int qa = code & 3, qb = (code >> 2) & 3;
            const int qr = (code >> 4) & 3, qs = (code >> 6) & 3;
            // full 2x2 gates in NAMED registers (no runtime-indexed locals)
            const cpx A00 = R[l*4+qa][0][0], A01 = R[l*4+qa][0][1];
            const cpx A10 = R[l*4+qa][1][0], A11 = R[l*4+qa][1][1];
            const cpx B00 = R[l*4+qb][0][0], B01 = R[l*4+qb][0][1];
            const cpx B10 = R[l*4+qb][1][0], B11 = R[l*4+qb][1][1];
            const cpx C00 = R[l*4+qr][0][0], C01 = R[l*4+qr][0][1];
            const cpx C10 = R[l*4+qr][1][0], C11 = R[l*4+qr][1][1];
            const cpx D00 = R[l*4+qs][0][0], D01 = R[l*4+qs][0][1];
            const cpx D10 = R[l*4+qs][1][0], D11 = R[l*4+qs][1][1];
            const float isc = ISc[l], iss = ISs[l];
            const int uAi = (((i >> (3 - qa)) & 1) << 1) | ((i >> (3 - qb)) & 1);
            const int uBi = (((i >> (3 - qr)) & 1) << 1) | ((i >> (3 - qs)) & 1);
            const cpx ra0 = (uAi & 2) ? A10 : A00, ra1 = (uAi & 2) ? A11 : A01;
            const cpx rb0 = (uAi & 1) ? B10 : B00, rb1 = (uAi & 1) ? B11 : B01;
            const cpx rr0 = (uBi & 2) ? C10 : C00, rr1 = (uBi & 2) ? C11 : C01;
            const cpx rs0 = (uBi & 1) ? D10 : D00, rs1 = (uBi & 1) ? D11 : D01;
            #pragma unroll
            for (int jj = 0; jj < 4; ++jj) {
                const int j = j0 + jj;
                const int uAj = (((j >> (3 - qa)) & 1) << 1) | ((j >> (3 - qb)) & 1);
                const int uBj = (((j >> (3 - qr)) & 1) << 1) | ((j >> (3 - qs)) & 1);
                cpx ga;
                if (uAj == 0)      ga = cmul(ra0, rb0);
                else if (uAj == 3) ga = cmul(ra1, rb1);
                else {
                    const cpx k1 = cmul(ra0, rb1), k2 = cmul(ra1, rb0);
                    const cpx tc = (uAj == 1) ? k1 : k2;   // * cos
                    const cpx ts = (uAj == 1) ? k2 : k1;   // * i sin
                    ga.re = isc * tc.re - iss * ts.im;
                    ga.im = isc * tc.im + iss * ts.re;
                }
                const cpx gb = cmul((uBj & 2) ? rr1 : rr0, (uBj & 1) ? rs1 : rs0);
                Lm[l][i][j] = cmul(ga, gb);
            }
        }
        WSYNC;

        // ---- Phase C: P1[m] = L[2m+1]*L[2m] (3 interleaved, 4 cols/lane) ----
        {
            cpx acc[3][4] = {};
            for (int k = 0; k < 16; ++k) {
                #pragma unroll
                for (int m = 0; m < 3; ++m) {
                    const cpx a = Lm[2 * m + 1][i][k];
                    #pragma unroll
                    for (int jj = 0; jj < 4; ++jj)
                        acc[m][jj] = cfma_(acc[m][jj], a, Lm[2 * m][k][j0 + jj]);
                }
            }
            #pragma unroll
            for (int m = 0; m < 3; ++m)
                #pragma unroll
                for (int jj = 0; jj < 4; ++jj)
                    P1[m][i][j0 + jj] = acc[m][jj];
        }
        WSYNC;

        // ---- Phase D: D = P1[1]*P1[0] ----
        {
            cpx acc[4] = {};
            for (int k = 0; k < 16; ++k) {
                const cpx a = P1[1][i][k];
                #pragma unroll
                for (int jj = 0; jj < 4; ++jj)
                    acc[jj] = cfma_(acc[jj], a, P1[0][k][j0 + jj]);
            }
            #pragma unroll
            for (int jj = 0; jj < 4; ++jj) Dm[i][j0 + jj] = acc[jj];
        }
        WSYNC;

        // ---- Phase E: W = P1[2]*D ----
        {
            cpx acc[4] = {};
            for (int k = 0; k < 16; ++k) {
                const cpx a = P1[2][i][k];
                #pragma unroll
                for (int jj = 0; jj < 4; ++jj)
                    acc[jj] = cfma_(acc[jj], a, Dm[k][j0 + jj]);
            }
            #pragma unroll
            for (int jj = 0; jj < 4; ++jj) Wf[i][j0 + jj] = acc[jj];
        }
        WSYNC;

        // ---- Phase F: M[i][j] = sum_k zk conj(W[k][i]) W[k][j] ----
        {
            cpx acc[4] = {};
            for (int k = 0; k < 16; ++k) {
                const float zk = (k < 8) ? 1.f : -1.f;
                const cpx a = Wf[k][i];
                #pragma unroll
                for (int jj = 0; jj < 4; ++jj) {
                    const cpx b = Wf[k][j0 + jj];
                    acc[jj].re += zk * (a.re * b.re + a.im * b.im);  // conj(a)*b
                    acc[jj].im += zk * (a.re * b.im - a.im * b.re);
                }
            }
            #pragma unroll
            for (int jj = 0; jj < 4; ++jj) Mm[i][j0 + jj] = acc[jj];
        }
        WSYNC;

        // ---- Phase G: Pauli traces, 4 p's per lane ----
        #pragma unroll
        for (int e = 0; e < 4; ++e) {
            const int p = (tid << 2) | e;
            float accre = 0.f;
            for (int col = 0; col < 16; ++col) {
                int row = 0;
                cpx val = {1.f, 0.f};
                #pragma unroll
                for (int k = 0; k < 4; ++k) {
                    const int pk = (p >> (6 - 2 * k)) & 3;
                    const int b = (col >> (3 - k)) & 1;
                    int rb = b;
                    if (pk == 1) {
                        rb = b ^ 1;
                    } else if (pk == 2) {
                        rb = b ^ 1;
                        const cpx fc = {0.f, b ? -1.f : 1.f};
                        val = cmul(val, fc);
                    } else if (pk == 3) {
                        if (b) { val.re = -val.re; val.im = -val.im; }
                    }
                    row |= rb << (3 - k);
                }
                const cpx mv = Mm[col][row];
                accre += mv.re * val.re - mv.im * val.im;
            }
            cp[p] = accre * (1.f / 16.f);
        }
        WSYNC;

        // ---- Phase H: collapse via compile-time table ----
        for (int t = tid; t < 125; t += 64) {
            const int cnt = TAB.cnt[t];
            float s = 0.f;
            for (int k = 0; k < cnt; ++k)      // ascending: deterministic
                s += cp[TAB.idx[t][k]];
            cf[t] = s;
        }
    }

    __syncthreads();   // the ONLY block-wide barrier

    // ================= EVAL FINISH (waves 1-7) =============================
    if (tid < 64) return;
    if (gidx >= B2) return;

    float2 res;
    #pragma unroll
    for (int e = 0; e < 2; ++e) {
        float Z = 0.f;
        #pragma unroll
        for (int a = 0; a <= 4; ++a)
            #pragma unroll
            for (int b = 0; b <= 4 - a; ++b)
                #pragma unroll
                for (int c = 0; c <= 4 - a - b; ++c)
                    Z = fmaf(cf[(a * 5 + b) * 5 + c],
                             xp[e][a] * yp[e][b] * zp[e][c], Z);
        const float noise = 0.04472135954999579f * (Z * Z - 1.f) * 0.25f;
        const float v = scale * (Z + noise) + bias;
        if (e) res.y = v; else res.x = v;
    }
    out2[gidx] = res;
}

extern "C" void kernel_launch(void* const* d_in, const int* in_sizes, int n_in,
                              void* d_out, int out_size, void* d_ws, size_t ws_size,
                              hipStream_t stream) {
    const float* inputs  = (const float*)d_in[0];   // [B,2] f32
    const float* w_U     = (const float*)d_in[1];   // [6]
    const float* w_RXZX  = (const float*)d_in[2];   // [6,4,3]
    const float* scale_p = (const float*)d_in[3];   // [1]
    const float* bias_p  = (const float*)d_in[4];   // [1]
    float* out = (float*)d_out;

    const int B  = in_sizes[0] / 2;                 // elements
    const int B2 = B / 2;                           // float4 units (2 el/thread)
    const int nblocks = (B2 + 447) / 448;           // 448 eval threads/block

    fused_kernel<<<nblocks, 512, 0, stream>>>(
        (const float4*)inputs, w_U, w_RXZX, scale_p, bias_p, (float2*)out, B2);
}